// Round 13
// baseline (2213.646 us; speedup 1.0000x reference)
//
#include <hip/hip_runtime.h>

#define NFULL 33024
#define FPS_T 768
#define BST   99072    // per-batch stride in XYZ SoA: 3*33024

typedef float v2f __attribute__((ext_vector_type(2)));
static __device__ __forceinline__ v2f mk2(float a, float b) { v2f r; r.x = a; r.y = b; return r; }

// ---- x1[b,o,k] = sum_i f[b,i] * ps_w[i,o,k] + ps_b[o] ; col = o*256+k ----
__global__ void k_ps(const float* __restrict__ feat,
                     const float* __restrict__ psw,
                     const float* __restrict__ psb,
                     float* __restrict__ out)
{
    __shared__ float fs[16384];   // all of f (32x512), 64 KB
    const int tid = threadIdx.x;
    for (int k = tid; k < 16384; k += 256) fs[k] = feat[k];
    __syncthreads();
    const int col = blockIdx.x * 256 + tid;    // 0..32767
    float acc[32];
    #pragma unroll
    for (int b = 0; b < 32; ++b) acc[b] = 0.f;
    for (int i = 0; i < 512; i += 4) {
        const float w0 = psw[(i+0)*32768 + col];
        const float w1 = psw[(i+1)*32768 + col];
        const float w2 = psw[(i+2)*32768 + col];
        const float w3 = psw[(i+3)*32768 + col];
        #pragma unroll
        for (int b = 0; b < 32; ++b) {
            const float4 f4 = *(const float4*)&fs[b*512 + i];
            acc[b] += f4.x*w0 + f4.y*w1 + f4.z*w2 + f4.w*w3;
        }
    }
    const float bias = psb[col >> 8];
    #pragma unroll
    for (int b = 0; b < 32; ++b) out[b*32768 + col] = acc[b] + bias;
}

// ---- fb[wsel][b,o] = sum_{i<512} f[b,i] * w[o*640 + 128 + i]  (fr-fold) ----
__global__ void k_fb(const float* __restrict__ feat,
                     const float* __restrict__ wa, const float* __restrict__ wb,
                     const float* __restrict__ wc, const float* __restrict__ wd,
                     float* __restrict__ fb)
{
    const int tid = blockIdx.x * 256 + threadIdx.x;  // 0..16383
    const int wsel = tid >> 12;
    const int r = tid & 4095;
    const int b = r >> 7, o = r & 127;
    const float* w = (wsel == 0 ? wa : wsel == 1 ? wb : wsel == 2 ? wc : wd) + o*640 + 128;
    const float* f = feat + b*512;
    float acc = 0.f;
    for (int i = 0; i < 512; i += 4) {
        const float4 wv = *(const float4*)(w + i);
        const float4 fv = *(const float4*)(f + i);
        acc += wv.x*fv.x + wv.y*fv.y + wv.z*fv.z + wv.w*fv.w;
    }
    fb[tid] = acc;
}

// ---- out[b,o,n] = relu?( sum_i w[o,i]*x[b,i,n] + bias[o] + fb[b,o] + add[b,o,n] )
__global__ void k_conv(const float* __restrict__ x,
                       const float* __restrict__ w,
                       const float* __restrict__ bias,
                       const float* __restrict__ fb,
                       const float* __restrict__ add,
                       float* __restrict__ out,
                       const int O, const int K, const int ldw, const int relu)
{
    const int bo = blockIdx.x;
    const int b = bo / O;
    const int o = bo - b * O;
    const int n = threadIdx.x;
    const float* __restrict__ wr = w + o * ldw;
    const float* __restrict__ xb = x + (b * K) * 256 + n;
    float acc = 0.f;
    for (int i = 0; i < K; i += 4) {
        const float4 wv = *(const float4*)(wr + i);
        acc += wv.x * xb[(i+0) << 8];
        acc += wv.y * xb[(i+1) << 8];
        acc += wv.z * xb[(i+2) << 8];
        acc += wv.w * xb[(i+3) << 8];
    }
    acc += bias[o];
    if (fb)   acc += fb[b * O + o];
    if (add)  acc += add[bo * 256 + n];
    if (relu) acc = fmaxf(acc, 0.f);
    out[bo * 256 + n] = acc;
}

// ---- pcd transpose -> d_out ; completion points -> XYZ SoA [0,256) ----
__global__ void k_pcd(const float* __restrict__ comp,
                      float* __restrict__ pcd_out,
                      float* __restrict__ XYZ)
{
    const int tid = blockIdx.x * 256 + threadIdx.x;  // 0..8191
    const int b = tid >> 8, n = tid & 255;
    const float cx = comp[(b*3+0)*256 + n];
    const float cy = comp[(b*3+1)*256 + n];
    const float cz = comp[(b*3+2)*256 + n];
    pcd_out[tid*3+0] = cx; pcd_out[tid*3+1] = cy; pcd_out[tid*3+2] = cz;
    float* Xb = XYZ + b*BST;
    Xb[n]           = cx;
    Xb[33024  + n]  = cy;
    Xb[66048  + n]  = cz;
}

// ---- partial (AoS) -> XYZ SoA [256,33024) per batch (bitwise) ----
__global__ void k_copy(const float* __restrict__ partial, float* __restrict__ XYZ)
{
    const int p = blockIdx.x*256 + threadIdx.x;   // 0..1048575 (32*32768)
    const int b = p >> 15, i = p & 32767;
    const float x = partial[p*3+0];
    const float y = partial[p*3+1];
    const float z = partial[p*3+2];
    float* Xb = XYZ + b*BST;
    Xb[256 + i]          = x;
    Xb[33024 + 256 + i]  = y;
    Xb[66048 + 256 + i]  = z;
}

// ================= farthest point sampling =================
// One 768-thread block per batch: 12 waves = 3 waves/SIMD (r12 at T=512 was
// latency-bound: packed math cut VALU 9% with ZERO time change). r9/r12
// discipline kept: ZERO persistent per-thread registers (d in LDS private
// slots -> cannot spill; r10's T=768 failure was d-in-registers at VGPR=84).
// LDS: d 132KB + z[0:6144) 24KB + red = 156.5KB < 160KB. x/y (+z tail)
// stream from the L2-resident SoA. 43 points/thread = 10 float4 groups
// (stride 3072) + 3 coalesced singles. Ascending code == ascending global
// index per thread -> strict-> scan + min-index tie-break == np.argmax
// first-max. Distance math bitwise-np-exact (packed lanes are independent
// IEEE ops, fp contract off; no fma).

#define FBODY(xx, yy, zz, dd, cc) { \
    const float dx = __fsub_rn((xx), lx); \
    const float dy = __fsub_rn((yy), ly); \
    const float dz = __fsub_rn((zz), lz); \
    const float dist = __fadd_rn(__fadd_rn(__fmul_rn(dx,dx), __fmul_rn(dy,dy)), \
                                 __fmul_rn(dz,dz)); \
    dd = fminf(dd, dist); \
    if (dd > bestv) { bestv = dd; bestc = (cc); } }

// 4 points via 2 packed lanes; ZP = z source (zls for jo<2, Zb else)
#define FPS_GRP(jo, ZP) { \
    const int off = (jo)*3072 + t4; \
    const float4 x4 = *(const float4*)(Xb + off); \
    const float4 y4 = *(const float4*)(Yb + off); \
    const float4 z4 = *(const float4*)((ZP) + off); \
    float4 d4 = *(float4*)(dls + off); \
    v2f da, db; \
    { \
      _Pragma("clang fp contract(off)") \
      const v2f dxa = mk2(x4.x, x4.y) - lx2, dxb = mk2(x4.z, x4.w) - lx2; \
      const v2f dya = mk2(y4.x, y4.y) - ly2, dyb = mk2(y4.z, y4.w) - ly2; \
      const v2f dza = mk2(z4.x, z4.y) - lz2, dzb = mk2(z4.z, z4.w) - lz2; \
      const v2f sa = (dxa*dxa + dya*dya) + dza*dza; \
      const v2f sb = (dxb*dxb + dyb*dyb) + dzb*dzb; \
      da = __builtin_elementwise_min(mk2(d4.x, d4.y), sa); \
      db = __builtin_elementwise_min(mk2(d4.z, d4.w), sb); \
    } \
    d4.x = da.x; d4.y = da.y; d4.z = db.x; d4.w = db.y; \
    *(float4*)(dls + off) = d4; \
    if (da.x > bestv) { bestv = da.x; bestc = (jo)*4 + 0; } \
    if (da.y > bestv) { bestv = da.y; bestc = (jo)*4 + 1; } \
    if (db.x > bestv) { bestv = db.x; bestc = (jo)*4 + 2; } \
    if (db.y > bestv) { bestv = db.y; bestc = (jo)*4 + 3; } }

__launch_bounds__(FPS_T)
__global__ void k_fps(const float* __restrict__ XYZ, float* __restrict__ outp)
{
    __shared__ __align__(16) float dls[NFULL];   // 132,096 B: the d array
    __shared__ __align__(16) float zls[6144];    //  24,576 B: z for p<6144
    __shared__ float redv[2][16];
    __shared__ int   redi[2][16];

    const int b = blockIdx.x;
    const int t = threadIdx.x;
    const int t4 = t << 2;
    const float* __restrict__ Xb = XYZ + b*BST;
    const float* __restrict__ Yb = Xb + 33024;
    const float* __restrict__ Zb = Xb + 66048;
    const float NEG = -__builtin_inff();

    {   // init d = 1e10 over this thread's private slots; stage z slice
        const float4 v = make_float4(1.0e10f, 1.0e10f, 1.0e10f, 1.0e10f);
        #pragma unroll
        for (int jo = 0; jo < 10; ++jo) *(float4*)(dls + jo*3072 + t4) = v;
        dls[30720 + t] = 1.0e10f;
        dls[31488 + t] = 1.0e10f;
        dls[32256 + t] = 1.0e10f;
        for (int k = t; k < 6144; k += FPS_T) zls[k] = Zb[k];
    }
    __syncthreads();

    int last = 0;
    float* __restrict__ po = outp + b * (512*3);
    for (int s = 0; s < 512; ++s) {
        const float lx = Xb[last];    // broadcast L2 hits
        const float ly = Yb[last];
        const float lz = Zb[last];
        if (t == 0) { po[s*3+0] = lx; po[s*3+1] = ly; po[s*3+2] = lz; }
        if (s == 511) break;
        const v2f lx2 = mk2(lx, lx), ly2 = mk2(ly, ly), lz2 = mk2(lz, lz);

        float bestv = NEG;
        int   bestc = 0x7FFFFFFF;
        // np order: dist = (dx*dx + dy*dy) + dz*dz, no fma; strict-> scan
        FPS_GRP(0, zls) FPS_GRP(1, zls)
        FPS_GRP(2, Zb)  FPS_GRP(3, Zb)  FPS_GRP(4, Zb)
        FPS_GRP(5, Zb)  FPS_GRP(6, Zb)  FPS_GRP(7, Zb)
        FPS_GRP(8, Zb)  FPS_GRP(9, Zb)
        {   // singles: p = 30720 + k*768 + t, codes 40..42 (coalesced)
            const int o0 = 30720 + t;
            float dd0 = dls[o0];
            FBODY(Xb[o0], Yb[o0], Zb[o0], dd0, 40)
            dls[o0] = dd0;
            const int o1 = 31488 + t;
            float dd1 = dls[o1];
            FBODY(Xb[o1], Yb[o1], Zb[o1], dd1, 41)
            dls[o1] = dd1;
            const int o2 = 32256 + t;
            float dd2 = dls[o2];
            FBODY(Xb[o2], Yb[o2], Zb[o2], dd2, 42)
            dls[o2] = dd2;
        }
        // decode code -> global point index
        int besti = (bestc < 40) ? ((bestc >> 2)*3072 + t4 + (bestc & 3))
                                 : (30720 + (bestc - 40)*768 + t);

        // wave (64-lane) argmax reduce, min-index tie-break
        #pragma unroll
        for (int m = 1; m < 64; m <<= 1) {
            const float ov = __shfl_xor(bestv, m, 64);
            const int   oi = __shfl_xor(besti, m, 64);
            if (ov > bestv || (ov == bestv && oi < besti)) { bestv = ov; besti = oi; }
        }
        const int bank = s & 1;
        if ((t & 63) == 0) { redv[bank][t >> 6] = bestv; redi[bank][t >> 6] = besti; }
        __syncthreads();
        // every wave redundantly reduces the 12 partials (no 2nd barrier;
        // banks are step-parity double-buffered)
        {
            const int lane = t & 63;
            float v = (lane < 12) ? redv[bank][lane] : NEG;
            int   i = (lane < 12) ? redi[bank][lane] : 0x7FFFFFFF;
            #pragma unroll
            for (int m = 1; m < 16; m <<= 1) {
                const float ov = __shfl_xor(v, m, 64);
                const int   oi = __shfl_xor(i, m, 64);
                if (ov > v || (ov == v && oi < i)) { v = ov; i = oi; }
            }
            last = __shfl(i, 0, 64);
        }
    }
}

extern "C" void kernel_launch(void* const* d_in, const int* in_sizes, int n_in,
                              void* d_out, int out_size, void* d_ws, size_t ws_size,
                              hipStream_t stream)
{
    const float* feat    = (const float*)d_in[0];
    const float* partial = (const float*)d_in[1];
    const float* ps_w    = (const float*)d_in[2];
    const float* ps_b    = (const float*)d_in[3];
    const float* m1_w1   = (const float*)d_in[4];
    const float* m1_b1   = (const float*)d_in[5];
    const float* m1_w2   = (const float*)d_in[6];
    const float* m1_b2   = (const float*)d_in[7];
    const float* m1_ws   = (const float*)d_in[8];
    const float* m1_bs   = (const float*)d_in[9];
    const float* m2_w1   = (const float*)d_in[10];
    const float* m2_b1   = (const float*)d_in[11];
    const float* m2_w2   = (const float*)d_in[12];
    const float* m2_b2   = (const float*)d_in[13];
    const float* m2_ws   = (const float*)d_in[14];
    const float* m2_bs   = (const float*)d_in[15];
    const float* m3_w1   = (const float*)d_in[16];
    const float* m3_b1   = (const float*)d_in[17];
    const float* m3_w2   = (const float*)d_in[18];
    const float* m3_b2   = (const float*)d_in[19];
    const float* m3_ws   = (const float*)d_in[20];
    const float* m3_bs   = (const float*)d_in[21];
    const float* m4_w1   = (const float*)d_in[22];
    const float* m4_b1   = (const float*)d_in[23];
    const float* m4_w2   = (const float*)d_in[24];
    const float* m4_b2   = (const float*)d_in[25];

    float* ws = (float*)d_ws;
    float* XYZ = ws;              // 32*3*33024 = 3,170,304 floats (SoA per batch)
    float* A  = ws + 3170304;     // 1,048,576
    float* B  = ws + 4218880;     // 1,048,576
    float* C  = ws + 5267456;     // 1,048,576
    float* FB = ws + 6316032;     // 4*4096 (m1_w1, m1_ws, m3_w1, m3_ws folds)

    float* out = (float*)d_out;   // [0,24576) pcd ; [24576,73728) p0

    k_ps  <<<128,  256, 0, stream>>>(feat, ps_w, ps_b, A);
    k_fb  <<<64,   256, 0, stream>>>(feat, m1_w1, m1_ws, m3_w1, m3_ws, FB);
    k_copy<<<4096, 256, 0, stream>>>(partial, XYZ);

    // m1 (fr folded into FB)
    k_conv<<<32*128, 256, 0, stream>>>(A, m1_w1, m1_b1, FB,       nullptr, B, 128, 128, 640, 1);
    k_conv<<<32*128, 256, 0, stream>>>(A, m1_ws, m1_bs, FB+4096,  nullptr, C, 128, 128, 640, 0);
    k_conv<<<32*128, 256, 0, stream>>>(B, m1_w2, m1_b2, nullptr,  C,       A, 128, 128, 128, 0);
    // m2
    k_conv<<<32*64,  256, 0, stream>>>(A, m2_w1, m2_b1, nullptr,  nullptr, B, 64,  128, 128, 1);
    k_conv<<<32*128, 256, 0, stream>>>(A, m2_ws, m2_bs, nullptr,  nullptr, C, 128, 128, 128, 0);
    k_conv<<<32*128, 256, 0, stream>>>(B, m2_w2, m2_b2, nullptr,  C,       A, 128, 64,  64,  0);
    // m3 (fr folded)
    k_conv<<<32*128, 256, 0, stream>>>(A, m3_w1, m3_b1, FB+8192,  nullptr, B, 128, 128, 640, 1);
    k_conv<<<32*128, 256, 0, stream>>>(A, m3_ws, m3_bs, FB+12288, nullptr, C, 128, 128, 640, 0);
    k_conv<<<32*128, 256, 0, stream>>>(B, m3_w2, m3_b2, nullptr,  C,       A, 128, 128, 128, 0);
    // m4
    k_conv<<<32*64,  256, 0, stream>>>(A, m4_w1, m4_b1, nullptr,  nullptr, B, 64,  128, 128, 1);
    k_conv<<<32*3,   256, 0, stream>>>(B, m4_w2, m4_b2, nullptr,  nullptr, C, 3,   64,  64,  0);

    k_pcd <<<32, 256, 0, stream>>>(C, out, XYZ);
    k_fps <<<32, FPS_T, 0, stream>>>(XYZ, out + 24576);
}